// Round 16
// baseline (407.656 us; speedup 1.0000x reference)
//
#include <hip/hip_runtime.h>
#include <hip/hip_bf16.h>
#include <cstdint>
#include <cstddef>

// Problem constants
#define NROWS 8192
#define DIM   2048
#define HIDN  1024
#define QKV3  3072
#define EPSV  1e-5f

typedef __attribute__((ext_vector_type(8))) short bf16x8;
typedef __attribute__((ext_vector_type(8))) unsigned short u16x8;
typedef __attribute__((ext_vector_type(4))) float f32x4;

__device__ __forceinline__ unsigned short f2bf(float x) {
    __hip_bfloat16 h = __float2bfloat16(x);
    return *reinterpret_cast<unsigned short*>(&h);
}
__device__ __forceinline__ float bf2f(unsigned short u) {
    return __uint_as_float((unsigned)u << 16);
}

__device__ __forceinline__ void gload_lds16(const void* g, void* l) {
    __builtin_amdgcn_global_load_lds(
        (const __attribute__((address_space(1))) void*)g,
        (__attribute__((address_space(3))) void*)l, 16, 0, 0);
}

template <int N> __device__ __forceinline__ void vmwait() {
    if constexpr (N == 8)      asm volatile("s_waitcnt vmcnt(8)" ::: "memory");
    else if constexpr (N == 4) asm volatile("s_waitcnt vmcnt(4)" ::: "memory");
    else if constexpr (N == 2) asm volatile("s_waitcnt vmcnt(2)" ::: "memory");
    else if constexpr (N == 0) asm volatile("s_waitcnt vmcnt(0)" ::: "memory");
}
__device__ __forceinline__ void barrier_mem() {
    asm volatile("s_barrier" ::: "memory");
}

// -------- prep: activations f32->bf16 + all 4 weight transposes, one kernel ----
__global__ __launch_bounds__(256) void prep(
    const float* __restrict__ cnn, unsigned short* __restrict__ Abf_c,
    const float* __restrict__ mlp, unsigned short* __restrict__ Abf_m,
    const float* __restrict__ Wcq, unsigned short* __restrict__ WqT_c,
    const float* __restrict__ Wmq, unsigned short* __restrict__ WqT_m,
    const float* __restrict__ Wcp, unsigned short* __restrict__ WpT_c,
    const float* __restrict__ Wmp, unsigned short* __restrict__ WpT_m) {
    __shared__ float tile[32][129];
    const int bid = blockIdx.x;
    const int t = threadIdx.x;
    if (bid < 16384) {
        const int which = bid >> 13;
        const long b = bid & 8191;
        const float* in = which ? mlp : cnn;
        unsigned short* out = which ? Abf_m : Abf_c;
        const long base = (b * 256 + t) * 8;
        float4 a = *(const float4*)(in + base);
        float4 v = *(const float4*)(in + base + 4);
        uint4 r;
        r.x = (unsigned)f2bf(a.x) | ((unsigned)f2bf(a.y) << 16);
        r.y = (unsigned)f2bf(a.z) | ((unsigned)f2bf(a.w) << 16);
        r.z = (unsigned)f2bf(v.x) | ((unsigned)f2bf(v.y) << 16);
        r.w = (unsigned)f2bf(v.z) | ((unsigned)f2bf(v.w) << 16);
        *(uint4*)(out + base) = r;
        return;
    }
    int l = bid - 16384;
    const float* in;
    unsigned short* out;
    int R, C, nbc;
    if (l < 3072) {
        const int wqq = l / 1536;
        l -= wqq * 1536;
        in = wqq ? Wmq : Wcq; out = wqq ? WqT_m : WqT_c; R = DIM; C = QKV3; nbc = 96;
    } else {
        l -= 3072;
        const int wp = l / 512;
        l -= wp * 512;
        in = wp ? Wmp : Wcp; out = wp ? WpT_m : WpT_c; R = HIDN; C = DIM; nbc = 64;
    }
    const int c0 = (l % nbc) * 32, r0 = (l / nbc) * 128;
#pragma unroll
    for (int i = 0; i < 16; ++i) {
        const int idx = t + i * 256;
        const int rr = idx >> 5, cc = idx & 31;
        tile[cc][rr] = in[(size_t)(r0 + rr) * C + c0 + cc];
    }
    __syncthreads();
#pragma unroll
    for (int k2 = 0; k2 < 2; ++k2) {
        const int u = t + k2 * 256;
        const int row = u >> 4, ch = u & 15;
        const float* p = &tile[row][ch * 8];
        u16x8 r;
#pragma unroll
        for (int k = 0; k < 8; ++k) r[k] = f2bf(p[k]);
        *(u16x8*)(out + (size_t)(c0 + row) * R + r0 + ch * 8) = r;
    }
}

// ============== 256x256 8-phase bf16 GEMM (C = A * Bt^T + bias [+resid]) =======
// K-loop byte-identical to the verified round-9/12/14/15 kernel.
// NEW (this round): bx-MAJOR block decomposition within each XCD's contiguous
// swizzle range -- concurrent blocks on an XCD share ONE B-panel (1 MB,
// L2-resident, 32x reuse) instead of thrashing 12.6 MB of B through L2.
// Targets the ~8 TB/s staging-read demand that L3 was serving.

__device__ __forceinline__ void stage_half(const unsigned short* __restrict__ G,
                                           int ldK, int rowBase, int kt,
                                           short* ldsHalf, int tid) {
#pragma unroll
    for (int i = 0; i < 2; ++i) {
        const int c = i * 512 + tid;            // 16-byte chunk index (0..1023)
        const int r = c >> 3;                   // row 0..127
        const int jl = (c & 7) ^ (r & 7);       // logical k-slot for this phys slot
        const unsigned short* src = G + (size_t)(rowBase + r) * ldK + kt + jl * 8;
        char* dst = (char*)ldsHalf + (size_t)((i * 512 + (tid & 0x1C0)) * 16);
        gload_lds16(src, dst);
    }
}

__device__ __forceinline__ void load_a4(const short* sAb, int rowA, int o0, int mbase,
                                        bf16x8 (&a)[4][2]) {
#pragma unroll
    for (int m = 0; m < 4; ++m) {
        const char* p = (const char*)sAb + rowA + (mbase + m) * 4096;
        a[m][0] = *(const bf16x8*)(p + o0);
        a[m][1] = *(const bf16x8*)(p + (o0 ^ 64));
    }
}
__device__ __forceinline__ void load_b2(const short* sBb, int rowB, int o0, int nbase,
                                        bf16x8 (&b)[4][2]) {
#pragma unroll
    for (int n = 0; n < 2; ++n) {
        const char* p = (const char*)sBb + rowB + (nbase + n) * 8192;
        b[nbase + n][0] = *(const bf16x8*)(p + o0);
        b[nbase + n][1] = *(const bf16x8*)(p + (o0 ^ 64));
    }
}

// kk OUTERMOST: 8 independent MFMAs between dependent accumulate pairs
#define QUAD(mq, nq)                                                          \
    __builtin_amdgcn_s_setprio(1);                                            \
    _Pragma("unroll") for (int kk_ = 0; kk_ < 2; ++kk_)                       \
    _Pragma("unroll") for (int n_ = 0; n_ < 2; ++n_)                          \
    _Pragma("unroll") for (int m_ = 0; m_ < 4; ++m_)                          \
        acc[(mq) + m_][(nq) + n_] = __builtin_amdgcn_mfma_f32_16x16x32_bf16(  \
            a[m_][kk_], b[(nq) + n_][kk_], acc[(mq) + m_][(nq) + n_], 0, 0, 0); \
    __builtin_amdgcn_s_setprio(0);

// MODE 0: steady | MODE 1: tile T-2 (stage ph1/ph2 only; ph4 vm4)
// MODE 2: tile T-1 (no stages; ph1 vm2, ph2 vm0; no ph4 post-read)
#define KTILE(BUF, MODE, KT1, KT2)                                            \
    /* ph1 */                                                                 \
    load_a4(&sA[BUF][0], rowA, o0, 0, a);                                     \
    if constexpr ((MODE) <= 1)                                                \
        stage_half(Bt, K, tn + 128, (KT1), &sB[(BUF) ^ 1][8192], tid);        \
    if constexpr ((MODE) == 2) { vmwait<2>(); } else { vmwait<8>(); }         \
    barrier_mem();                                                            \
    QUAD(0, 0);                                                               \
    /* ph2 */                                                                 \
    load_b2(&sB[BUF][0], rowB, o0, 2, b);                                     \
    if constexpr ((MODE) <= 1)                                                \
        stage_half(A, K, tm + 128, (KT1), &sA[(BUF) ^ 1][8192], tid);         \
    if constexpr ((MODE) == 2) { vmwait<0>(); } else { vmwait<8>(); }         \
    barrier_mem();                                                            \
    QUAD(0, 2);                                                               \
    /* ph3 */                                                                 \
    load_a4(&sA[BUF][0], rowA, o0, 4, a);                                     \
    if constexpr ((MODE) == 0)                                                \
        stage_half(A, K, tm, (KT2), &sA[BUF][0], tid);                        \
    barrier_mem();                                                            \
    QUAD(4, 0);                                                               \
    /* ph4 */                                                                 \
    if constexpr ((MODE) == 0) {                                              \
        stage_half(Bt, K, tn, (KT2), &sB[BUF][0], tid);                       \
        vmwait<8>();                                                          \
    }                                                                         \
    if constexpr ((MODE) == 1) { vmwait<4>(); }                               \
    barrier_mem();                                                            \
    if constexpr ((MODE) <= 1)                                                \
        load_b2(&sB[(BUF) ^ 1][0], rowB, o0, 0, b);  /* b01(t+1) post-read */ \
    QUAD(4, 2);

template <int EPI>
__global__ __launch_bounds__(512, 2) void gemm256(
    const unsigned short* __restrict__ A0, const unsigned short* __restrict__ B0t,
    const float* __restrict__ bias0, const float* __restrict__ res0, void* __restrict__ C0,
    const unsigned short* __restrict__ A1, const unsigned short* __restrict__ B1t,
    const float* __restrict__ bias1, const float* __restrict__ res1, void* __restrict__ C1,
    int M, int N, int K, int nbx) {
    __shared__ __align__(16) char smem[131072];
    short (*sA)[16384] = reinterpret_cast<short (*)[16384]>(smem);
    short (*sB)[16384] = reinterpret_cast<short (*)[16384]>(smem + 65536);
    float* smemF = reinterpret_cast<float*>(smem);

    const int tid = threadIdx.x;
    // bijective XCD swizzle (gridDim.x % 8 == 0 for all our launches)
    const int nwg = gridDim.x;
    const int ob = blockIdx.x;
    const int swz = (ob & 7) * (nwg >> 3) + (ob >> 3);
    const int per = nbx * (M >> 8);
    const int which = swz >= per ? 1 : 0;
    const int rem = swz - which * per;
    // bx-MAJOR: concurrent blocks within an XCD share one B-panel (L2-resident)
    const int nbm = M >> 8;
    const int bx = rem / nbm, by = rem % nbm;
    const int tm = by << 8, tn = bx << 8;

    const unsigned short* __restrict__ A  = which ? A1 : A0;
    const unsigned short* __restrict__ Bt = which ? B1t : B0t;
    const float* __restrict__ bias  = which ? bias1 : bias0;
    const float* __restrict__ resid = which ? res1 : res0;

    const int w = tid >> 6, l = tid & 63;
    const int wm = w >> 2, wn = w & 3;           // 2 x 4 waves
    const int lg = l >> 4, lr = l & 15;
    const int o0 = (lg ^ (lr & 7)) << 4;         // swizzled k-slot byte offset
    const int rowA = (16 * wm + lr) << 7;        // byte offset of lane's A row
    const int rowB = (16 * wn + lr) << 7;

    f32x4 acc[8][4] = {};
    bf16x8 a[4][2], b[4][2];

    const int T = K >> 6;                        // K-tiles (even, >= 4)

    // prologue: halves Ah0(0),Bh0(0),Bh1(0),Ah1(0),Ah0(1),Bh0(1); vm8 retires
    // Ah0(0)+Bh0(0); barrier; pre-read b01(0).
    stage_half(A,  K, tm,       0,  &sA[0][0],    tid);
    stage_half(Bt, K, tn,       0,  &sB[0][0],    tid);
    stage_half(Bt, K, tn + 128, 0,  &sB[0][8192], tid);
    stage_half(A,  K, tm + 128, 0,  &sA[0][8192], tid);
    stage_half(A,  K, tm,       64, &sA[1][0],    tid);
    stage_half(Bt, K, tn,       64, &sB[1][0],    tid);
    vmwait<8>();
    barrier_mem();
    load_b2(&sB[0][0], rowB, o0, 0, b);          // b01(0)

    int kt = 0;
    for (int tt = 0; tt + 4 <= T; tt += 2) {
        KTILE(0, 0, kt + 64, kt + 128);
        KTILE(1, 0, kt + 128, kt + 192);
        kt += 128;
    }
    // peel tiles T-2 (buf0) and T-1 (buf1)
    KTILE(0, 1, kt + 64, 0);
    KTILE(1, 2, 0, 0);

    // ---- epilogue via LDS (C/D map: col = lane&15, row = 4*(l>>4)+j) ----
    barrier_mem();                               // all frag reads of smem done
    const int crow_l = 16 * wm + 4 * lg;         // local row within half (0..127)
    const int ccol_l = 16 * wn + lr;             // local col (0..255)
#pragma unroll
    for (int half = 0; half < 2; ++half) {
#pragma unroll
        for (int mi2 = 0; mi2 < 4; ++mi2) {
            const int lrow = 32 * mi2 + crow_l;
#pragma unroll
            for (int ni = 0; ni < 4; ++ni) {
                const int colg = ccol_l + 64 * ni;
                const float bb = bias[tn + colg];
                const f32x4 v = acc[half * 4 + mi2][ni];
#pragma unroll
                for (int j = 0; j < 4; ++j)
                    smemF[(lrow + j) * 256 + colg] = v[j] + bb;
            }
        }
        barrier_mem();
        const int rowb = tm + half * 128;
        if constexpr (EPI == 0) {
            unsigned short* C = (unsigned short*)(which ? C1 : C0);
#pragma unroll
            for (int i = 0; i < 8; ++i) {
                const int f8 = tid + i * 512;    // 8-element group index
                const int row = f8 >> 5, c8 = (f8 & 31) * 8;
                const float* p = smemF + row * 256 + c8;
                u16x8 r;
#pragma unroll
                for (int k = 0; k < 8; ++k) r[k] = f2bf(p[k]);
                *(u16x8*)(C + (size_t)(rowb + row) * N + tn + c8) = r;
            }
        } else {
            float* C = (float*)(which ? C1 : C0);
#pragma unroll
            for (int i = 0; i < 16; ++i) {
                const int f4 = tid + i * 512;    // float4 group index
                const int row = f4 >> 6, c4 = (f4 & 63) * 4;
                const size_t idx = (size_t)(rowb + row) * N + tn + c4;
                float4 v = *(const float4*)(smemF + row * 256 + c4);
                const float4 rr = *(const float4*)(resid + idx);
                v.x += rr.x; v.y += rr.y; v.z += rr.z; v.w += rr.w;
                *(float4*)(C + idx) = v;
            }
        }
        barrier_mem();                           // before next half overwrites
    }
}

// ---------------- per-row 16-head cross attention + layernorm ------------------
// 512 threads: BOTH paths run concurrently (path = tid>>8).
__global__ __launch_bounds__(512) void attn_ln(const unsigned short* __restrict__ qkv_c,
                                               const unsigned short* __restrict__ qkv_m,
                                               const float* __restrict__ g1,
                                               const float* __restrict__ be1,
                                               const float* __restrict__ g2,
                                               const float* __restrict__ be2,
                                               unsigned short* __restrict__ ln1,
                                               unsigned short* __restrict__ ln2) {
    __shared__ float qc[48 * 68];
    __shared__ float qm[48 * 68];
    __shared__ float sS[2][16 * 17];
    __shared__ float sP[2][16 * 17];
    __shared__ float red[2][8];
    const int t = threadIdx.x;
    const long b = blockIdx.x;
    const int p = t >> 8, tl = t & 255;

    {
        const unsigned short* src = (p ? qkv_m : qkv_c) + b * QKV3;
        float* dst = p ? qm : qc;
#pragma unroll
        for (int it = 0; it < 3; ++it) {
            const int i0 = tl * 4 + it * 1024;
            ushort4 v4 = *(const ushort4*)(src + i0);
            const int o = (i0 >> 6) * 68 + (i0 & 63);
            dst[o + 0] = bf2f(v4.x); dst[o + 1] = bf2f(v4.y);
            dst[o + 2] = bf2f(v4.z); dst[o + 3] = bf2f(v4.w);
        }
    }
    __syncthreads();

    const float* q  = p ? qm : qc;
    const float* kv = p ? qc : qm;
    const float* k  = kv + 16 * 68;
    const float* v  = kv + 32 * 68;
    const float* gw = p ? g2 : g1;
    const float* bw = p ? be2 : be1;
    unsigned short* out = p ? ln2 : ln1;
    float* mS = sS[p];
    float* mP = sP[p];
    float* mR = red[p];

    const int h = tl >> 4, gg = tl & 15;
    {
        const float* qr = q + h * 68;
        const float* kr = k + gg * 68;
        float s = 0.f;
#pragma unroll
        for (int d = 0; d < 64; d += 4) {
            const float4 qv = *(const float4*)(qr + d);
            const float4 kvv = *(const float4*)(kr + d);
            s += qv.x * kvv.x + qv.y * kvv.y + qv.z * kvv.z + qv.w * kvv.w;
        }
        mS[h * 17 + gg] = s * 0.125f;
    }
    __syncthreads();
    {
        float mx = -1e30f;
#pragma unroll
        for (int j = 0; j < 16; ++j) mx = fmaxf(mx, mS[h * 17 + j]);
        float sum = 0.f;
#pragma unroll
        for (int j = 0; j < 16; ++j) sum += __expf(mS[h * 17 + j] - mx);
        mP[h * 17 + gg] = __expf(mS[h * 17 + gg] - mx) / sum;
    }
    __syncthreads();
    float xs[4];
    float lsum = 0.f, lss = 0.f;
#pragma unroll
    for (int r = 0; r < 4; ++r) {
        const int i = tl + 256 * r;
        const int d = i >> 4, hh = i & 15;
        float accv = 0.f;
#pragma unroll
        for (int g2i = 0; g2i < 16; ++g2i) accv += mP[hh * 17 + g2i] * v[g2i * 68 + d];
        xs[r] = accv;
        lsum += accv;
        lss += accv * accv;
    }
#pragma unroll
    for (int off = 32; off > 0; off >>= 1) {
        lsum += __shfl_down(lsum, off);
        lss += __shfl_down(lss, off);
    }
    if ((t & 63) == 0) {
        mR[((t >> 6) & 3) * 2] = lsum;
        mR[((t >> 6) & 3) * 2 + 1] = lss;
    }
    __syncthreads();
    const float tot = mR[0] + mR[2] + mR[4] + mR[6];
    const float tot2 = mR[1] + mR[3] + mR[5] + mR[7];
    const float mean = tot * (1.f / 1024.f);
    const float var = tot2 * (1.f / 1024.f) - mean * mean;
    const float rstd = rsqrtf(var + EPSV);
#pragma unroll
    for (int r = 0; r < 4; ++r) {
        const int i = tl + 256 * r;
        const float y = (xs[r] - mean) * rstd * gw[i] + bw[i];
        out[b * 1024 + i] = f2bf(y);
    }
}

// -------------------------------- launch ---------------------------------------
extern "C" void kernel_launch(void* const* d_in, const int* in_sizes, int n_in,
                              void* d_out, int out_size, void* d_ws, size_t ws_size,
                              hipStream_t stream) {
    const float* cnn    = (const float*)d_in[0];
    const float* mlp    = (const float*)d_in[1];
    const float* W_cqkv = (const float*)d_in[2];
    const float* b_cqkv = (const float*)d_in[3];
    const float* W_mqkv = (const float*)d_in[4];
    const float* b_mqkv = (const float*)d_in[5];
    const float* g1     = (const float*)d_in[6];
    const float* be1    = (const float*)d_in[7];
    const float* g2     = (const float*)d_in[8];
    const float* be2    = (const float*)d_in[9];
    const float* W_cproj = (const float*)d_in[10];
    const float* b_cproj = (const float*)d_in[11];
    const float* W_mproj = (const float*)d_in[12];
    const float* b_mproj = (const float*)d_in[13];
    float* out = (float*)d_out;
    char* ws = (char*)d_ws;

    unsigned short* Abf_c = (unsigned short*)(ws + 0);           // 33,554,432 B
    unsigned short* Abf_m = (unsigned short*)(ws + 33554432);    // 33,554,432 B
    unsigned short* WqT_c = (unsigned short*)(ws + 67108864);    // 12,582,912 B
    unsigned short* WqT_m = (unsigned short*)(ws + 79691776);    // 12,582,912 B
    unsigned short* qkv_c = (unsigned short*)(ws + 92274688);    // 50,331,648 B
    unsigned short* qkv_m = (unsigned short*)(ws + 142606336);   // 50,331,648 B
    unsigned short* ln1   = (unsigned short*)(ws + 0);           // alias Abf_c
    unsigned short* ln2   = (unsigned short*)(ws + 16777216);    // alias Abf_c
    // proj weights transposed up-front: own region (do NOT alias live buffers)
    unsigned short* WpT_c = (unsigned short*)(ws + 192937984);   // 4,194,304 B
    unsigned short* WpT_m = (unsigned short*)(ws + 197132288);   // 4,194,304 B

    // 1. all conversions/transposes in one kernel (independent of GEMMs)
    prep<<<20480, 256, 0, stream>>>(cnn, Abf_c, mlp, Abf_m,
                                    W_cqkv, WqT_c, W_mqkv, WqT_m,
                                    W_cproj, WpT_c, W_mproj, WpT_m);

    // 2. fused QKV GEMM pair: (8192x2048)*(2048x3072) x2, grid 768
    gemm256<0><<<768, 512, 0, stream>>>(Abf_c, WqT_c, b_cqkv, nullptr, qkv_c,
                                        Abf_m, WqT_m, b_mqkv, nullptr, qkv_m,
                                        NROWS, QKV3, DIM, QKV3 / 256);

    // 3. attention + layernorm, both paths concurrent (512 thr)
    attn_ln<<<NROWS, 512, 0, stream>>>(qkv_c, qkv_m, g1, be1, g2, be2, ln1, ln2);

    // 4. fused proj GEMM pair: (8192x1024)*(1024x2048) x2 + bias + residual
    gemm256<1><<<512, 512, 0, stream>>>(ln1, WpT_c, b_cproj, cnn, out,
                                        ln2, WpT_m, b_mproj, mlp, out + (size_t)NROWS * DIM,
                                        NROWS, DIM, HIDN, DIM / 256);
}

// Round 17
// 383.694 us; speedup vs baseline: 1.0625x; 1.0625x over previous
//
#include <hip/hip_runtime.h>
#include <hip/hip_bf16.h>
#include <cstdint>
#include <cstddef>

// Problem constants
#define NROWS 8192
#define DIM   2048
#define HIDN  1024
#define QKV3  3072
#define EPSV  1e-5f

typedef __attribute__((ext_vector_type(8))) short bf16x8;
typedef __attribute__((ext_vector_type(8))) unsigned short u16x8;
typedef __attribute__((ext_vector_type(4))) float f32x4;

__device__ __forceinline__ unsigned short f2bf(float x) {
    __hip_bfloat16 h = __float2bfloat16(x);
    return *reinterpret_cast<unsigned short*>(&h);
}
__device__ __forceinline__ float bf2f(unsigned short u) {
    return __uint_as_float((unsigned)u << 16);
}

__device__ __forceinline__ void gload_lds16(const void* g, void* l) {
    __builtin_amdgcn_global_load_lds(
        (const __attribute__((address_space(1))) void*)g,
        (__attribute__((address_space(3))) void*)l, 16, 0, 0);
}

template <int N> __device__ __forceinline__ void vmwait() {
    if constexpr (N == 8)      asm volatile("s_waitcnt vmcnt(8)" ::: "memory");
    else if constexpr (N == 4) asm volatile("s_waitcnt vmcnt(4)" ::: "memory");
    else if constexpr (N == 2) asm volatile("s_waitcnt vmcnt(2)" ::: "memory");
    else if constexpr (N == 0) asm volatile("s_waitcnt vmcnt(0)" ::: "memory");
}
__device__ __forceinline__ void barrier_mem() {
    asm volatile("s_barrier" ::: "memory");
}

// -------- prep: activations f32->bf16 + all 4 weight transposes, one kernel ----
__global__ __launch_bounds__(256) void prep(
    const float* __restrict__ cnn, unsigned short* __restrict__ Abf_c,
    const float* __restrict__ mlp, unsigned short* __restrict__ Abf_m,
    const float* __restrict__ Wcq, unsigned short* __restrict__ WqT_c,
    const float* __restrict__ Wmq, unsigned short* __restrict__ WqT_m,
    const float* __restrict__ Wcp, unsigned short* __restrict__ WpT_c,
    const float* __restrict__ Wmp, unsigned short* __restrict__ WpT_m) {
    __shared__ float tile[32][129];
    const int bid = blockIdx.x;
    const int t = threadIdx.x;
    if (bid < 16384) {
        const int which = bid >> 13;
        const long b = bid & 8191;
        const float* in = which ? mlp : cnn;
        unsigned short* out = which ? Abf_m : Abf_c;
        const long base = (b * 256 + t) * 8;
        float4 a = *(const float4*)(in + base);
        float4 v = *(const float4*)(in + base + 4);
        uint4 r;
        r.x = (unsigned)f2bf(a.x) | ((unsigned)f2bf(a.y) << 16);
        r.y = (unsigned)f2bf(a.z) | ((unsigned)f2bf(a.w) << 16);
        r.z = (unsigned)f2bf(v.x) | ((unsigned)f2bf(v.y) << 16);
        r.w = (unsigned)f2bf(v.z) | ((unsigned)f2bf(v.w) << 16);
        *(uint4*)(out + base) = r;
        return;
    }
    int l = bid - 16384;
    const float* in;
    unsigned short* out;
    int R, C, nbc;
    if (l < 3072) {
        const int wqq = l / 1536;
        l -= wqq * 1536;
        in = wqq ? Wmq : Wcq; out = wqq ? WqT_m : WqT_c; R = DIM; C = QKV3; nbc = 96;
    } else {
        l -= 3072;
        const int wp = l / 512;
        l -= wp * 512;
        in = wp ? Wmp : Wcp; out = wp ? WpT_m : WpT_c; R = HIDN; C = DIM; nbc = 64;
    }
    const int c0 = (l % nbc) * 32, r0 = (l / nbc) * 128;
#pragma unroll
    for (int i = 0; i < 16; ++i) {
        const int idx = t + i * 256;
        const int rr = idx >> 5, cc = idx & 31;
        tile[cc][rr] = in[(size_t)(r0 + rr) * C + c0 + cc];
    }
    __syncthreads();
#pragma unroll
    for (int k2 = 0; k2 < 2; ++k2) {
        const int u = t + k2 * 256;
        const int row = u >> 4, ch = u & 15;
        const float* p = &tile[row][ch * 8];
        u16x8 r;
#pragma unroll
        for (int k = 0; k < 8; ++k) r[k] = f2bf(p[k]);
        *(u16x8*)(out + (size_t)(c0 + row) * R + r0 + ch * 8) = r;
    }
}

// ============== 256x256 8-phase bf16 GEMM (C = A * Bt^T + bias [+resid]) =======
// K-loop + by-major decomposition byte-identical to the verified round-15
// kernel (512 thr = 8 waves, BK=64, LDS 128 KiB dbuf, T2 XOR swizzle,
// pre-barrier reads, vmcnt chain ph1/ph2/ph4 = 8, tails {8,8,-,4}/{2,0,-,-}).

__device__ __forceinline__ void stage_half(const unsigned short* __restrict__ G,
                                           int ldK, int rowBase, int kt,
                                           short* ldsHalf, int tid) {
#pragma unroll
    for (int i = 0; i < 2; ++i) {
        const int c = i * 512 + tid;            // 16-byte chunk index (0..1023)
        const int r = c >> 3;                   // row 0..127
        const int jl = (c & 7) ^ (r & 7);       // logical k-slot for this phys slot
        const unsigned short* src = G + (size_t)(rowBase + r) * ldK + kt + jl * 8;
        char* dst = (char*)ldsHalf + (size_t)((i * 512 + (tid & 0x1C0)) * 16);
        gload_lds16(src, dst);
    }
}

__device__ __forceinline__ void load_a4(const short* sAb, int rowA, int o0, int mbase,
                                        bf16x8 (&a)[4][2]) {
#pragma unroll
    for (int m = 0; m < 4; ++m) {
        const char* p = (const char*)sAb + rowA + (mbase + m) * 4096;
        a[m][0] = *(const bf16x8*)(p + o0);
        a[m][1] = *(const bf16x8*)(p + (o0 ^ 64));
    }
}
__device__ __forceinline__ void load_b2(const short* sBb, int rowB, int o0, int nbase,
                                        bf16x8 (&b)[4][2]) {
#pragma unroll
    for (int n = 0; n < 2; ++n) {
        const char* p = (const char*)sBb + rowB + (nbase + n) * 8192;
        b[nbase + n][0] = *(const bf16x8*)(p + o0);
        b[nbase + n][1] = *(const bf16x8*)(p + (o0 ^ 64));
    }
}

// kk OUTERMOST: 8 independent MFMAs between dependent accumulate pairs
#define QUAD(mq, nq)                                                          \
    __builtin_amdgcn_s_setprio(1);                                            \
    _Pragma("unroll") for (int kk_ = 0; kk_ < 2; ++kk_)                       \
    _Pragma("unroll") for (int n_ = 0; n_ < 2; ++n_)                          \
    _Pragma("unroll") for (int m_ = 0; m_ < 4; ++m_)                          \
        acc[(mq) + m_][(nq) + n_] = __builtin_amdgcn_mfma_f32_16x16x32_bf16(  \
            a[m_][kk_], b[(nq) + n_][kk_], acc[(mq) + m_][(nq) + n_], 0, 0, 0); \
    __builtin_amdgcn_s_setprio(0);

// MODE 0: steady | MODE 1: tile T-2 (stage ph1/ph2 only; ph4 vm4)
// MODE 2: tile T-1 (no stages; ph1 vm2, ph2 vm0; no ph4 post-read)
#define KTILE(BUF, MODE, KT1, KT2)                                            \
    /* ph1 */                                                                 \
    load_a4(&sA[BUF][0], rowA, o0, 0, a);                                     \
    if constexpr ((MODE) <= 1)                                                \
        stage_half(Bt, K, tn + 128, (KT1), &sB[(BUF) ^ 1][8192], tid);        \
    if constexpr ((MODE) == 2) { vmwait<2>(); } else { vmwait<8>(); }         \
    barrier_mem();                                                            \
    QUAD(0, 0);                                                               \
    /* ph2 */                                                                 \
    load_b2(&sB[BUF][0], rowB, o0, 2, b);                                     \
    if constexpr ((MODE) <= 1)                                                \
        stage_half(A, K, tm + 128, (KT1), &sA[(BUF) ^ 1][8192], tid);         \
    if constexpr ((MODE) == 2) { vmwait<0>(); } else { vmwait<8>(); }         \
    barrier_mem();                                                            \
    QUAD(0, 2);                                                               \
    /* ph3 */                                                                 \
    load_a4(&sA[BUF][0], rowA, o0, 4, a);                                     \
    if constexpr ((MODE) == 0)                                                \
        stage_half(A, K, tm, (KT2), &sA[BUF][0], tid);                        \
    barrier_mem();                                                            \
    QUAD(4, 0);                                                               \
    /* ph4 */                                                                 \
    if constexpr ((MODE) == 0) {                                              \
        stage_half(Bt, K, tn, (KT2), &sB[BUF][0], tid);                       \
        vmwait<8>();                                                          \
    }                                                                         \
    if constexpr ((MODE) == 1) { vmwait<4>(); }                               \
    barrier_mem();                                                            \
    if constexpr ((MODE) <= 1)                                                \
        load_b2(&sB[(BUF) ^ 1][0], rowB, o0, 0, b);  /* b01(t+1) post-read */ \
    QUAD(4, 2);

template <int EPI>
__global__ __launch_bounds__(512, 2) void gemm256(
    const unsigned short* __restrict__ A0, const unsigned short* __restrict__ B0t,
    const float* __restrict__ bias0, const float* __restrict__ res0, void* __restrict__ C0,
    const unsigned short* __restrict__ A1, const unsigned short* __restrict__ B1t,
    const float* __restrict__ bias1, const float* __restrict__ res1, void* __restrict__ C1,
    int M, int N, int K, int nbx) {
    __shared__ __align__(16) char smem[131072];
    short (*sA)[16384] = reinterpret_cast<short (*)[16384]>(smem);
    short (*sB)[16384] = reinterpret_cast<short (*)[16384]>(smem + 65536);
    float* smemF = reinterpret_cast<float*>(smem);

    const int tid = threadIdx.x;
    // bijective XCD swizzle (gridDim.x % 8 == 0 for all our launches)
    const int nwg = gridDim.x;
    const int ob = blockIdx.x;
    const int swz = (ob & 7) * (nwg >> 3) + (ob >> 3);
    const int per = nbx * (M >> 8);
    const int which = swz >= per ? 1 : 0;
    const int rem = swz - which * per;
    const int by = rem / nbx, bx = rem % nbx;    // by-major (round-15 proven)
    const int tm = by << 8, tn = bx << 8;

    const unsigned short* __restrict__ A  = which ? A1 : A0;
    const unsigned short* __restrict__ Bt = which ? B1t : B0t;
    const float* __restrict__ bias  = which ? bias1 : bias0;
    const float* __restrict__ resid = which ? res1 : res0;

    const int w = tid >> 6, l = tid & 63;
    const int wm = w >> 2, wn = w & 3;           // 2 x 4 waves
    const int lg = l >> 4, lr = l & 15;
    const int o0 = (lg ^ (lr & 7)) << 4;         // swizzled k-slot byte offset
    const int rowA = (16 * wm + lr) << 7;        // byte offset of lane's A row
    const int rowB = (16 * wn + lr) << 7;

    f32x4 acc[8][4] = {};
    bf16x8 a[4][2], b[4][2];

    const int T = K >> 6;                        // K-tiles (even, >= 4)

    // prologue: halves Ah0(0),Bh0(0),Bh1(0),Ah1(0),Ah0(1),Bh0(1); vm8 retires
    // Ah0(0)+Bh0(0); barrier; pre-read b01(0).
    stage_half(A,  K, tm,       0,  &sA[0][0],    tid);
    stage_half(Bt, K, tn,       0,  &sB[0][0],    tid);
    stage_half(Bt, K, tn + 128, 0,  &sB[0][8192], tid);
    stage_half(A,  K, tm + 128, 0,  &sA[0][8192], tid);
    stage_half(A,  K, tm,       64, &sA[1][0],    tid);
    stage_half(Bt, K, tn,       64, &sB[1][0],    tid);
    vmwait<8>();
    barrier_mem();
    load_b2(&sB[0][0], rowB, o0, 0, b);          // b01(0)

    int kt = 0;
    for (int tt = 0; tt + 4 <= T; tt += 2) {
        KTILE(0, 0, kt + 64, kt + 128);
        KTILE(1, 0, kt + 128, kt + 192);
        kt += 128;
    }
    // peel tiles T-2 (buf0) and T-1 (buf1)
    KTILE(0, 1, kt + 64, 0);
    KTILE(1, 2, 0, 0);

    // ---- epilogue via LDS (C/D map: col = lane&15, row = 4*(l>>4)+j) ----
    barrier_mem();                               // all frag reads of smem done
    const int crow_l = 16 * wm + 4 * lg;         // local row within half (0..127)
    const int ccol_l = 16 * wn + lr;             // local col (0..255)
#pragma unroll
    for (int half = 0; half < 2; ++half) {
#pragma unroll
        for (int mi2 = 0; mi2 < 4; ++mi2) {
            const int lrow = 32 * mi2 + crow_l;
#pragma unroll
            for (int ni = 0; ni < 4; ++ni) {
                const int colg = ccol_l + 64 * ni;
                const float bb = bias[tn + colg];
                const f32x4 v = acc[half * 4 + mi2][ni];
#pragma unroll
                for (int j = 0; j < 4; ++j)
                    smemF[(lrow + j) * 256 + colg] = v[j] + bb;
            }
        }
        barrier_mem();
        const int rowb = tm + half * 128;
        if constexpr (EPI == 0) {
            unsigned short* C = (unsigned short*)(which ? C1 : C0);
#pragma unroll
            for (int i = 0; i < 8; ++i) {
                const int f8 = tid + i * 512;    // 8-element group index
                const int row = f8 >> 5, c8 = (f8 & 31) * 8;
                const float* p = smemF + row * 256 + c8;
                u16x8 r;
#pragma unroll
                for (int k = 0; k < 8; ++k) r[k] = f2bf(p[k]);
                *(u16x8*)(C + (size_t)(rowb + row) * N + tn + c8) = r;
            }
        } else {
            float* C = (float*)(which ? C1 : C0);
#pragma unroll
            for (int i = 0; i < 16; ++i) {
                const int f4 = tid + i * 512;    // float4 group index
                const int row = f4 >> 6, c4 = (f4 & 63) * 4;
                const size_t idx = (size_t)(rowb + row) * N + tn + c4;
                float4 v = *(const float4*)(smemF + row * 256 + c4);
                const float4 rr = *(const float4*)(resid + idx);
                v.x += rr.x; v.y += rr.y; v.z += rr.z; v.w += rr.w;
                *(float4*)(C + idx) = v;
            }
        }
        barrier_mem();                           // before next half overwrites
    }
}

// ---------------- per-row 16-head cross attention + layernorm ------------------
// 512 threads: BOTH paths concurrent (path = tid>>8).  PV remapped: thread
// owns head hh=tl&15 and 4 consecutive d (d0=(tl>>4)*4) -> V reads are 16
// float4 LDS loads (16-lane broadcast, bank-disjoint across q4 groups)
// instead of 64 scalar reads.
__global__ __launch_bounds__(512) void attn_ln(const unsigned short* __restrict__ qkv_c,
                                               const unsigned short* __restrict__ qkv_m,
                                               const float* __restrict__ g1,
                                               const float* __restrict__ be1,
                                               const float* __restrict__ g2,
                                               const float* __restrict__ be2,
                                               unsigned short* __restrict__ ln1,
                                               unsigned short* __restrict__ ln2) {
    __shared__ float qc[48 * 68];
    __shared__ float qm[48 * 68];
    __shared__ float sS[2][16 * 17];
    __shared__ float sP[2][16 * 17];
    __shared__ float red[2][8];
    const int t = threadIdx.x;
    const long b = blockIdx.x;
    const int p = t >> 8, tl = t & 255;

    {
        const unsigned short* src = (p ? qkv_m : qkv_c) + b * QKV3;
        float* dst = p ? qm : qc;
#pragma unroll
        for (int it = 0; it < 3; ++it) {
            const int i0 = tl * 4 + it * 1024;
            ushort4 v4 = *(const ushort4*)(src + i0);
            const int o = (i0 >> 6) * 68 + (i0 & 63);
            dst[o + 0] = bf2f(v4.x); dst[o + 1] = bf2f(v4.y);
            dst[o + 2] = bf2f(v4.z); dst[o + 3] = bf2f(v4.w);
        }
    }
    __syncthreads();

    const float* q  = p ? qm : qc;
    const float* kv = p ? qc : qm;
    const float* k  = kv + 16 * 68;
    const float* v  = kv + 32 * 68;
    const float* gw = p ? g2 : g1;
    const float* bw = p ? be2 : be1;
    unsigned short* out = p ? ln2 : ln1;
    float* mS = sS[p];
    float* mP = sP[p];
    float* mR = red[p];

    const int h = tl >> 4, gg = tl & 15;
    // QK^T (float4 dot)
    {
        const float* qr = q + h * 68;
        const float* kr = k + gg * 68;
        float s = 0.f;
#pragma unroll
        for (int d = 0; d < 64; d += 4) {
            const float4 qv = *(const float4*)(qr + d);
            const float4 kvv = *(const float4*)(kr + d);
            s += qv.x * kvv.x + qv.y * kvv.y + qv.z * kvv.z + qv.w * kvv.w;
        }
        mS[h * 17 + gg] = s * 0.125f;
    }
    __syncthreads();
    // softmax over the 16 scores of head h
    {
        float mx = -1e30f;
#pragma unroll
        for (int j = 0; j < 16; ++j) mx = fmaxf(mx, mS[h * 17 + j]);
        float sum = 0.f;
#pragma unroll
        for (int j = 0; j < 16; ++j) sum += __expf(mS[h * 17 + j] - mx);
        mP[h * 17 + gg] = __expf(mS[h * 17 + gg] - mx) / sum;
    }
    __syncthreads();
    // PV (float4 over d) + LN partial sums.  Thread: hh = tl&15, d0 = (tl>>4)*4.
    const int hh = tl & 15, d0 = (tl >> 4) * 4;
    float a0 = 0.f, a1 = 0.f, a2 = 0.f, a3 = 0.f;
#pragma unroll
    for (int g2i = 0; g2i < 16; ++g2i) {
        const float pw = mP[hh * 17 + g2i];
        const float4 vv = *(const float4*)(v + g2i * 68 + d0);
        a0 += pw * vv.x; a1 += pw * vv.y; a2 += pw * vv.z; a3 += pw * vv.w;
    }
    float lsum = a0 + a1 + a2 + a3;
    float lss = a0 * a0 + a1 * a1 + a2 * a2 + a3 * a3;
#pragma unroll
    for (int off = 32; off > 0; off >>= 1) {
        lsum += __shfl_down(lsum, off);
        lss += __shfl_down(lss, off);
    }
    if ((t & 63) == 0) {
        mR[((t >> 6) & 3) * 2] = lsum;
        mR[((t >> 6) & 3) * 2 + 1] = lss;
    }
    __syncthreads();
    const float tot = mR[0] + mR[2] + mR[4] + mR[6];
    const float tot2 = mR[1] + mR[3] + mR[5] + mR[7];
    const float mean = tot * (1.f / 1024.f);
    const float var = tot2 * (1.f / 1024.f) - mean * mean;
    const float rstd = rsqrtf(var + EPSV);
    // output: element i = (d0+j)*16 + hh  (each of the 1024 covered once)
    const float av[4] = {a0, a1, a2, a3};
#pragma unroll
    for (int j = 0; j < 4; ++j) {
        const int i = (d0 + j) * 16 + hh;
        const float y = (av[j] - mean) * rstd * gw[i] + bw[i];
        out[b * 1024 + i] = f2bf(y);
    }
}

// -------------------------------- launch ---------------------------------------
extern "C" void kernel_launch(void* const* d_in, const int* in_sizes, int n_in,
                              void* d_out, int out_size, void* d_ws, size_t ws_size,
                              hipStream_t stream) {
    const float* cnn    = (const float*)d_in[0];
    const float* mlp    = (const float*)d_in[1];
    const float* W_cqkv = (const float*)d_in[2];
    const float* b_cqkv = (const float*)d_in[3];
    const float* W_mqkv = (const float*)d_in[4];
    const float* b_mqkv = (const float*)d_in[5];
    const float* g1     = (const float*)d_in[6];
    const float* be1    = (const float*)d_in[7];
    const float* g2     = (const float*)d_in[8];
    const float* be2    = (const float*)d_in[9];
    const float* W_cproj = (const float*)d_in[10];
    const float* b_cproj = (const float*)d_in[11];
    const float* W_mproj = (const float*)d_in[12];
    const float* b_mproj = (const float*)d_in[13];
    float* out = (float*)d_out;
    char* ws = (char*)d_ws;

    unsigned short* Abf_c = (unsigned short*)(ws + 0);           // 33,554,432 B
    unsigned short* Abf_m = (unsigned short*)(ws + 33554432);    // 33,554,432 B
    unsigned short* WqT_c = (unsigned short*)(ws + 67108864);    // 12,582,912 B
    unsigned short* WqT_m = (unsigned short*)(ws + 79691776);    // 12,582,912 B
    unsigned short* qkv_c = (unsigned short*)(ws + 92274688);    // 50,331,648 B
    unsigned short* qkv_m = (unsigned short*)(ws + 142606336);   // 50,331,648 B
    unsigned short* ln1   = (unsigned short*)(ws + 0);           // alias Abf_c
    unsigned short* ln2   = (unsigned short*)(ws + 16777216);    // alias Abf_c
    // proj weights transposed up-front: own region (do NOT alias live buffers)
    unsigned short* WpT_c = (unsigned short*)(ws + 192937984);   // 4,194,304 B
    unsigned short* WpT_m = (unsigned short*)(ws + 197132288);   // 4,194,304 B

    // 1. all conversions/transposes in one kernel (independent of GEMMs)
    prep<<<20480, 256, 0, stream>>>(cnn, Abf_c, mlp, Abf_m,
                                    W_cqkv, WqT_c, W_mqkv, WqT_m,
                                    W_cproj, WpT_c, W_mproj, WpT_m);

    // 2. fused QKV GEMM pair: (8192x2048)*(2048x3072) x2, grid 768
    gemm256<0><<<768, 512, 0, stream>>>(Abf_c, WqT_c, b_cqkv, nullptr, qkv_c,
                                        Abf_m, WqT_m, b_mqkv, nullptr, qkv_m,
                                        NROWS, QKV3, DIM, QKV3 / 256);

    // 3. attention + layernorm, both paths concurrent (512 thr)
    attn_ln<<<NROWS, 512, 0, stream>>>(qkv_c, qkv_m, g1, be1, g2, be2, ln1, ln2);

    // 4. fused proj GEMM pair: (8192x1024)*(1024x2048) x2 + bias + residual
    gemm256<1><<<512, 512, 0, stream>>>(ln1, WpT_c, b_cproj, cnn, out,
                                        ln2, WpT_m, b_mproj, mlp, out + (size_t)NROWS * DIM,
                                        NROWS, DIM, HIDN, DIM / 256);
}

// Round 18
// 383.502 us; speedup vs baseline: 1.0630x; 1.0005x over previous
//
#include <hip/hip_runtime.h>
#include <hip/hip_bf16.h>
#include <cstdint>
#include <cstddef>

// Problem constants
#define NROWS 8192
#define DIM   2048
#define HIDN  1024
#define QKV3  3072
#define EPSV  1e-5f

typedef __attribute__((ext_vector_type(8))) short bf16x8;
typedef __attribute__((ext_vector_type(8))) unsigned short u16x8;
typedef __attribute__((ext_vector_type(4))) float f32x4;

__device__ __forceinline__ unsigned short f2bf(float x) {
    __hip_bfloat16 h = __float2bfloat16(x);
    return *reinterpret_cast<unsigned short*>(&h);
}
__device__ __forceinline__ float bf2f(unsigned short u) {
    return __uint_as_float((unsigned)u << 16);
}

__device__ __forceinline__ void gload_lds16(const void* g, void* l) {
    __builtin_amdgcn_global_load_lds(
        (const __attribute__((address_space(1))) void*)g,
        (__attribute__((address_space(3))) void*)l, 16, 0, 0);
}

template <int N> __device__ __forceinline__ void vmwait() {
    if constexpr (N == 8)      asm volatile("s_waitcnt vmcnt(8)" ::: "memory");
    else if constexpr (N == 4) asm volatile("s_waitcnt vmcnt(4)" ::: "memory");
    else if constexpr (N == 2) asm volatile("s_waitcnt vmcnt(2)" ::: "memory");
    else if constexpr (N == 0) asm volatile("s_waitcnt vmcnt(0)" ::: "memory");
}
__device__ __forceinline__ void barrier_mem() {
    asm volatile("s_barrier" ::: "memory");
}

// -------- prep: weight transposes FIRST (heavy blocks), then activations ------
// blocks [0,3072): W_qkv^T x2 (128row x 32col tiles, 1536 each).
// [3072,4096): W_proj^T x2 (512 each).
// [4096,20480): activation cvt (two tensors, 8192 blocks each).
// Heavy transpose blocks scheduled first so they don't straggle the tail.
__global__ __launch_bounds__(256) void prep(
    const float* __restrict__ cnn, unsigned short* __restrict__ Abf_c,
    const float* __restrict__ mlp, unsigned short* __restrict__ Abf_m,
    const float* __restrict__ Wcq, unsigned short* __restrict__ WqT_c,
    const float* __restrict__ Wmq, unsigned short* __restrict__ WqT_m,
    const float* __restrict__ Wcp, unsigned short* __restrict__ WpT_c,
    const float* __restrict__ Wmp, unsigned short* __restrict__ WpT_m) {
    __shared__ float tile[32][129];
    const int bid = blockIdx.x;
    const int t = threadIdx.x;
    if (bid >= 4096) {
        const long bb = bid - 4096;
        const int which = bb >= 8192 ? 1 : 0;
        const long b = bb & 8191;
        const float* in = which ? mlp : cnn;
        unsigned short* out = which ? Abf_m : Abf_c;
        const long base = (b * 256 + t) * 8;
        float4 a = *(const float4*)(in + base);
        float4 v = *(const float4*)(in + base + 4);
        uint4 r;
        r.x = (unsigned)f2bf(a.x) | ((unsigned)f2bf(a.y) << 16);
        r.y = (unsigned)f2bf(a.z) | ((unsigned)f2bf(a.w) << 16);
        r.z = (unsigned)f2bf(v.x) | ((unsigned)f2bf(v.y) << 16);
        r.w = (unsigned)f2bf(v.z) | ((unsigned)f2bf(v.w) << 16);
        *(uint4*)(out + base) = r;
        return;
    }
    int l = bid;
    const float* in;
    unsigned short* out;
    int R, C, nbc;
    if (l < 3072) {
        const int wqq = l / 1536;
        l -= wqq * 1536;
        in = wqq ? Wmq : Wcq; out = wqq ? WqT_m : WqT_c; R = DIM; C = QKV3; nbc = 96;
    } else {
        l -= 3072;
        const int wp = l / 512;
        l -= wp * 512;
        in = wp ? Wmp : Wcp; out = wp ? WpT_m : WpT_c; R = HIDN; C = DIM; nbc = 64;
    }
    const int c0 = (l % nbc) * 32, r0 = (l / nbc) * 128;
#pragma unroll
    for (int i = 0; i < 16; ++i) {
        const int idx = t + i * 256;
        const int rr = idx >> 5, cc = idx & 31;
        tile[cc][rr] = in[(size_t)(r0 + rr) * C + c0 + cc];
    }
    __syncthreads();
#pragma unroll
    for (int k2 = 0; k2 < 2; ++k2) {
        const int u = t + k2 * 256;
        const int row = u >> 4, ch = u & 15;
        const float* p = &tile[row][ch * 8];
        u16x8 r;
#pragma unroll
        for (int k = 0; k < 8; ++k) r[k] = f2bf(p[k]);
        *(u16x8*)(out + (size_t)(c0 + row) * R + r0 + ch * 8) = r;
    }
}

// ============== 256x256 8-phase bf16 GEMM (C = A * Bt^T + bias [+resid]) =======
// K-loop + by-major decomposition byte-identical to the verified round-15/17
// kernel (512 thr = 8 waves, BK=64, LDS 128 KiB dbuf, T2 XOR swizzle,
// pre-barrier reads, vmcnt chain ph1/ph2/ph4 = 8, tails {8,8,-,4}/{2,0,-,-}).

__device__ __forceinline__ void stage_half(const unsigned short* __restrict__ G,
                                           int ldK, int rowBase, int kt,
                                           short* ldsHalf, int tid) {
#pragma unroll
    for (int i = 0; i < 2; ++i) {
        const int c = i * 512 + tid;            // 16-byte chunk index (0..1023)
        const int r = c >> 3;                   // row 0..127
        const int jl = (c & 7) ^ (r & 7);       // logical k-slot for this phys slot
        const unsigned short* src = G + (size_t)(rowBase + r) * ldK + kt + jl * 8;
        char* dst = (char*)ldsHalf + (size_t)((i * 512 + (tid & 0x1C0)) * 16);
        gload_lds16(src, dst);
    }
}

__device__ __forceinline__ void load_a4(const short* sAb, int rowA, int o0, int mbase,
                                        bf16x8 (&a)[4][2]) {
#pragma unroll
    for (int m = 0; m < 4; ++m) {
        const char* p = (const char*)sAb + rowA + (mbase + m) * 4096;
        a[m][0] = *(const bf16x8*)(p + o0);
        a[m][1] = *(const bf16x8*)(p + (o0 ^ 64));
    }
}
__device__ __forceinline__ void load_b2(const short* sBb, int rowB, int o0, int nbase,
                                        bf16x8 (&b)[4][2]) {
#pragma unroll
    for (int n = 0; n < 2; ++n) {
        const char* p = (const char*)sBb + rowB + (nbase + n) * 8192;
        b[nbase + n][0] = *(const bf16x8*)(p + o0);
        b[nbase + n][1] = *(const bf16x8*)(p + (o0 ^ 64));
    }
}

// kk OUTERMOST: 8 independent MFMAs between dependent accumulate pairs
#define QUAD(mq, nq)                                                          \
    __builtin_amdgcn_s_setprio(1);                                            \
    _Pragma("unroll") for (int kk_ = 0; kk_ < 2; ++kk_)                       \
    _Pragma("unroll") for (int n_ = 0; n_ < 2; ++n_)                          \
    _Pragma("unroll") for (int m_ = 0; m_ < 4; ++m_)                          \
        acc[(mq) + m_][(nq) + n_] = __builtin_amdgcn_mfma_f32_16x16x32_bf16(  \
            a[m_][kk_], b[(nq) + n_][kk_], acc[(mq) + m_][(nq) + n_], 0, 0, 0); \
    __builtin_amdgcn_s_setprio(0);

// MODE 0: steady | MODE 1: tile T-2 (stage ph1/ph2 only; ph4 vm4)
// MODE 2: tile T-1 (no stages; ph1 vm2, ph2 vm0; no ph4 post-read)
#define KTILE(BUF, MODE, KT1, KT2)                                            \
    /* ph1 */                                                                 \
    load_a4(&sA[BUF][0], rowA, o0, 0, a);                                     \
    if constexpr ((MODE) <= 1)                                                \
        stage_half(Bt, K, tn + 128, (KT1), &sB[(BUF) ^ 1][8192], tid);        \
    if constexpr ((MODE) == 2) { vmwait<2>(); } else { vmwait<8>(); }         \
    barrier_mem();                                                            \
    QUAD(0, 0);                                                               \
    /* ph2 */                                                                 \
    load_b2(&sB[BUF][0], rowB, o0, 2, b);                                     \
    if constexpr ((MODE) <= 1)                                                \
        stage_half(A, K, tm + 128, (KT1), &sA[(BUF) ^ 1][8192], tid);         \
    if constexpr ((MODE) == 2) { vmwait<0>(); } else { vmwait<8>(); }         \
    barrier_mem();                                                            \
    QUAD(0, 2);                                                               \
    /* ph3 */                                                                 \
    load_a4(&sA[BUF][0], rowA, o0, 4, a);                                     \
    if constexpr ((MODE) == 0)                                                \
        stage_half(A, K, tm, (KT2), &sA[BUF][0], tid);                        \
    barrier_mem();                                                            \
    QUAD(4, 0);                                                               \
    /* ph4 */                                                                 \
    if constexpr ((MODE) == 0) {                                              \
        stage_half(Bt, K, tn, (KT2), &sB[BUF][0], tid);                       \
        vmwait<8>();                                                          \
    }                                                                         \
    if constexpr ((MODE) == 1) { vmwait<4>(); }                               \
    barrier_mem();                                                            \
    if constexpr ((MODE) <= 1)                                                \
        load_b2(&sB[(BUF) ^ 1][0], rowB, o0, 0, b);  /* b01(t+1) post-read */ \
    QUAD(4, 2);

template <int EPI>
__global__ __launch_bounds__(512, 2) void gemm256(
    const unsigned short* __restrict__ A0, const unsigned short* __restrict__ B0t,
    const float* __restrict__ bias0, const float* __restrict__ res0, void* __restrict__ C0,
    const unsigned short* __restrict__ A1, const unsigned short* __restrict__ B1t,
    const float* __restrict__ bias1, const float* __restrict__ res1, void* __restrict__ C1,
    int M, int N, int K, int nbx) {
    __shared__ __align__(16) char smem[131072];
    short (*sA)[16384] = reinterpret_cast<short (*)[16384]>(smem);
    short (*sB)[16384] = reinterpret_cast<short (*)[16384]>(smem + 65536);
    float* smemF = reinterpret_cast<float*>(smem);

    const int tid = threadIdx.x;
    // bijective XCD swizzle (gridDim.x % 8 == 0 for all our launches)
    const int nwg = gridDim.x;
    const int ob = blockIdx.x;
    const int swz = (ob & 7) * (nwg >> 3) + (ob >> 3);
    const int per = nbx * (M >> 8);
    const int which = swz >= per ? 1 : 0;
    const int rem = swz - which * per;
    const int by = rem / nbx, bx = rem % nbx;    // by-major (round-15 proven)
    const int tm = by << 8, tn = bx << 8;

    const unsigned short* __restrict__ A  = which ? A1 : A0;
    const unsigned short* __restrict__ Bt = which ? B1t : B0t;
    const float* __restrict__ bias  = which ? bias1 : bias0;
    const float* __restrict__ resid = which ? res1 : res0;

    const int w = tid >> 6, l = tid & 63;
    const int wm = w >> 2, wn = w & 3;           // 2 x 4 waves
    const int lg = l >> 4, lr = l & 15;
    const int o0 = (lg ^ (lr & 7)) << 4;         // swizzled k-slot byte offset
    const int rowA = (16 * wm + lr) << 7;        // byte offset of lane's A row
    const int rowB = (16 * wn + lr) << 7;

    f32x4 acc[8][4] = {};
    bf16x8 a[4][2], b[4][2];

    const int T = K >> 6;                        // K-tiles (even, >= 4)

    // prologue: halves Ah0(0),Bh0(0),Bh1(0),Ah1(0),Ah0(1),Bh0(1); vm8 retires
    // Ah0(0)+Bh0(0); barrier; pre-read b01(0).
    stage_half(A,  K, tm,       0,  &sA[0][0],    tid);
    stage_half(Bt, K, tn,       0,  &sB[0][0],    tid);
    stage_half(Bt, K, tn + 128, 0,  &sB[0][8192], tid);
    stage_half(A,  K, tm + 128, 0,  &sA[0][8192], tid);
    stage_half(A,  K, tm,       64, &sA[1][0],    tid);
    stage_half(Bt, K, tn,       64, &sB[1][0],    tid);
    vmwait<8>();
    barrier_mem();
    load_b2(&sB[0][0], rowB, o0, 0, b);          // b01(0)

    int kt = 0;
    for (int tt = 0; tt + 4 <= T; tt += 2) {
        KTILE(0, 0, kt + 64, kt + 128);
        KTILE(1, 0, kt + 128, kt + 192);
        kt += 128;
    }
    // peel tiles T-2 (buf0) and T-1 (buf1)
    KTILE(0, 1, kt + 64, 0);
    KTILE(1, 2, 0, 0);

    // ---- epilogue via LDS (C/D map: col = lane&15, row = 4*(l>>4)+j) ----
    barrier_mem();                               // all frag reads of smem done
    const int crow_l = 16 * wm + 4 * lg;         // local row within half (0..127)
    const int ccol_l = 16 * wn + lr;             // local col (0..255)
#pragma unroll
    for (int half = 0; half < 2; ++half) {
#pragma unroll
        for (int mi2 = 0; mi2 < 4; ++mi2) {
            const int lrow = 32 * mi2 + crow_l;
#pragma unroll
            for (int ni = 0; ni < 4; ++ni) {
                const int colg = ccol_l + 64 * ni;
                const float bb = bias[tn + colg];
                const f32x4 v = acc[half * 4 + mi2][ni];
#pragma unroll
                for (int j = 0; j < 4; ++j)
                    smemF[(lrow + j) * 256 + colg] = v[j] + bb;
            }
        }
        barrier_mem();
        const int rowb = tm + half * 128;
        if constexpr (EPI == 0) {
            unsigned short* C = (unsigned short*)(which ? C1 : C0);
#pragma unroll
            for (int i = 0; i < 8; ++i) {
                const int f8 = tid + i * 512;    // 8-element group index
                const int row = f8 >> 5, c8 = (f8 & 31) * 8;
                const float* p = smemF + row * 256 + c8;
                u16x8 r;
#pragma unroll
                for (int k = 0; k < 8; ++k) r[k] = f2bf(p[k]);
                *(u16x8*)(C + (size_t)(rowb + row) * N + tn + c8) = r;
            }
        } else {
            float* C = (float*)(which ? C1 : C0);
#pragma unroll
            for (int i = 0; i < 16; ++i) {
                const int f4 = tid + i * 512;    // float4 group index
                const int row = f4 >> 6, c4 = (f4 & 63) * 4;
                const size_t idx = (size_t)(rowb + row) * N + tn + c4;
                float4 v = *(const float4*)(smemF + row * 256 + c4);
                const float4 rr = *(const float4*)(resid + idx);
                v.x += rr.x; v.y += rr.y; v.z += rr.z; v.w += rr.w;
                *(float4*)(C + idx) = v;
            }
        }
        barrier_mem();                           // before next half overwrites
    }
}

// ---------------- per-row 16-head cross attention + layernorm ------------------
// 512 threads: BOTH paths concurrent (path = tid>>8).  PV float4 remap
// (thread owns head hh=tl&15, d0=(tl>>4)*4).
__global__ __launch_bounds__(512) void attn_ln(const unsigned short* __restrict__ qkv_c,
                                               const unsigned short* __restrict__ qkv_m,
                                               const float* __restrict__ g1,
                                               const float* __restrict__ be1,
                                               const float* __restrict__ g2,
                                               const float* __restrict__ be2,
                                               unsigned short* __restrict__ ln1,
                                               unsigned short* __restrict__ ln2) {
    __shared__ float qc[48 * 68];
    __shared__ float qm[48 * 68];
    __shared__ float sS[2][16 * 17];
    __shared__ float sP[2][16 * 17];
    __shared__ float red[2][8];
    const int t = threadIdx.x;
    const long b = blockIdx.x;
    const int p = t >> 8, tl = t & 255;

    {
        const unsigned short* src = (p ? qkv_m : qkv_c) + b * QKV3;
        float* dst = p ? qm : qc;
#pragma unroll
        for (int it = 0; it < 3; ++it) {
            const int i0 = tl * 4 + it * 1024;
            ushort4 v4 = *(const ushort4*)(src + i0);
            const int o = (i0 >> 6) * 68 + (i0 & 63);
            dst[o + 0] = bf2f(v4.x); dst[o + 1] = bf2f(v4.y);
            dst[o + 2] = bf2f(v4.z); dst[o + 3] = bf2f(v4.w);
        }
    }
    __syncthreads();

    const float* q  = p ? qm : qc;
    const float* kv = p ? qc : qm;
    const float* k  = kv + 16 * 68;
    const float* v  = kv + 32 * 68;
    const float* gw = p ? g2 : g1;
    const float* bw = p ? be2 : be1;
    unsigned short* out = p ? ln2 : ln1;
    float* mS = sS[p];
    float* mP = sP[p];
    float* mR = red[p];

    const int h = tl >> 4, gg = tl & 15;
    {
        const float* qr = q + h * 68;
        const float* kr = k + gg * 68;
        float s = 0.f;
#pragma unroll
        for (int d = 0; d < 64; d += 4) {
            const float4 qv = *(const float4*)(qr + d);
            const float4 kvv = *(const float4*)(kr + d);
            s += qv.x * kvv.x + qv.y * kvv.y + qv.z * kvv.z + qv.w * kvv.w;
        }
        mS[h * 17 + gg] = s * 0.125f;
    }
    __syncthreads();
    {
        float mx = -1e30f;
#pragma unroll
        for (int j = 0; j < 16; ++j) mx = fmaxf(mx, mS[h * 17 + j]);
        float sum = 0.f;
#pragma unroll
        for (int j = 0; j < 16; ++j) sum += __expf(mS[h * 17 + j] - mx);
        mP[h * 17 + gg] = __expf(mS[h * 17 + gg] - mx) / sum;
    }
    __syncthreads();
    const int hh = tl & 15, d0 = (tl >> 4) * 4;
    float a0 = 0.f, a1 = 0.f, a2 = 0.f, a3 = 0.f;
#pragma unroll
    for (int g2i = 0; g2i < 16; ++g2i) {
        const float pw = mP[hh * 17 + g2i];
        const float4 vv = *(const float4*)(v + g2i * 68 + d0);
        a0 += pw * vv.x; a1 += pw * vv.y; a2 += pw * vv.z; a3 += pw * vv.w;
    }
    float lsum = a0 + a1 + a2 + a3;
    float lss = a0 * a0 + a1 * a1 + a2 * a2 + a3 * a3;
#pragma unroll
    for (int off = 32; off > 0; off >>= 1) {
        lsum += __shfl_down(lsum, off);
        lss += __shfl_down(lss, off);
    }
    if ((t & 63) == 0) {
        mR[((t >> 6) & 3) * 2] = lsum;
        mR[((t >> 6) & 3) * 2 + 1] = lss;
    }
    __syncthreads();
    const float tot = mR[0] + mR[2] + mR[4] + mR[6];
    const float tot2 = mR[1] + mR[3] + mR[5] + mR[7];
    const float mean = tot * (1.f / 1024.f);
    const float var = tot2 * (1.f / 1024.f) - mean * mean;
    const float rstd = rsqrtf(var + EPSV);
    const float av[4] = {a0, a1, a2, a3};
#pragma unroll
    for (int j = 0; j < 4; ++j) {
        const int i = (d0 + j) * 16 + hh;
        const float y = (av[j] - mean) * rstd * gw[i] + bw[i];
        out[b * 1024 + i] = f2bf(y);
    }
}

// -------------------------------- launch ---------------------------------------
extern "C" void kernel_launch(void* const* d_in, const int* in_sizes, int n_in,
                              void* d_out, int out_size, void* d_ws, size_t ws_size,
                              hipStream_t stream) {
    const float* cnn    = (const float*)d_in[0];
    const float* mlp    = (const float*)d_in[1];
    const float* W_cqkv = (const float*)d_in[2];
    const float* b_cqkv = (const float*)d_in[3];
    const float* W_mqkv = (const float*)d_in[4];
    const float* b_mqkv = (const float*)d_in[5];
    const float* g1     = (const float*)d_in[6];
    const float* be1    = (const float*)d_in[7];
    const float* g2     = (const float*)d_in[8];
    const float* be2    = (const float*)d_in[9];
    const float* W_cproj = (const float*)d_in[10];
    const float* b_cproj = (const float*)d_in[11];
    const float* W_mproj = (const float*)d_in[12];
    const float* b_mproj = (const float*)d_in[13];
    float* out = (float*)d_out;
    char* ws = (char*)d_ws;

    unsigned short* Abf_c = (unsigned short*)(ws + 0);           // 33,554,432 B
    unsigned short* Abf_m = (unsigned short*)(ws + 33554432);    // 33,554,432 B
    unsigned short* WqT_c = (unsigned short*)(ws + 67108864);    // 12,582,912 B
    unsigned short* WqT_m = (unsigned short*)(ws + 79691776);    // 12,582,912 B
    unsigned short* qkv_c = (unsigned short*)(ws + 92274688);    // 50,331,648 B
    unsigned short* qkv_m = (unsigned short*)(ws + 142606336);   // 50,331,648 B
    unsigned short* ln1   = (unsigned short*)(ws + 0);           // alias Abf_c
    unsigned short* ln2   = (unsigned short*)(ws + 16777216);    // alias Abf_c
    // proj weights transposed up-front: own region (do NOT alias live buffers)
    unsigned short* WpT_c = (unsigned short*)(ws + 192937984);   // 4,194,304 B
    unsigned short* WpT_m = (unsigned short*)(ws + 197132288);   // 4,194,304 B

    // 1. all conversions/transposes in one kernel (heavy transpose blocks first)
    prep<<<20480, 256, 0, stream>>>(cnn, Abf_c, mlp, Abf_m,
                                    W_cqkv, WqT_c, W_mqkv, WqT_m,
                                    W_cproj, WpT_c, W_mproj, WpT_m);

    // 2. fused QKV GEMM pair: (8192x2048)*(2048x3072) x2, grid 768
    gemm256<0><<<768, 512, 0, stream>>>(Abf_c, WqT_c, b_cqkv, nullptr, qkv_c,
                                        Abf_m, WqT_m, b_mqkv, nullptr, qkv_m,
                                        NROWS, QKV3, DIM, QKV3 / 256);

    // 3. attention + layernorm, both paths concurrent (512 thr)
    attn_ln<<<NROWS, 512, 0, stream>>>(qkv_c, qkv_m, g1, be1, g2, be2, ln1, ln2);

    // 4. fused proj GEMM pair: (8192x1024)*(1024x2048) x2 + bias + residual
    gemm256<1><<<512, 512, 0, stream>>>(ln1, WpT_c, b_cproj, cnn, out,
                                        ln2, WpT_m, b_mproj, mlp, out + (size_t)NROWS * DIM,
                                        NROWS, DIM, HIDN, DIM / 256);
}